// Round 1
// baseline (3562.928 us; speedup 1.0000x reference)
//
#include <hip/hip_runtime.h>
#include <math.h>

static constexpr int S    = 41;
static constexpr int DIN  = 1280;
static constexpr int DOUT = 1024;
static constexpr int HEADS = 4;
static constexpr int HC   = 256;

// ---------------- reduction helpers ----------------

__device__ __forceinline__ float warpReduceSum(float v) {
#pragma unroll
  for (int off = 32; off; off >>= 1) v += __shfl_down(v, off);
  return v;
}

__device__ __forceinline__ void blockReduce2(float& a, float& b) {
  a = warpReduceSum(a);
  b = warpReduceSum(b);
  __shared__ float red[8];
  int w = threadIdx.x >> 6, lane = threadIdx.x & 63;
  if (lane == 0) { red[w] = a; red[4 + w] = b; }
  __syncthreads();
  a = red[0] + red[1] + red[2] + red[3];
  b = red[4] + red[5] + red[6] + red[7];
}

__device__ __forceinline__ void blockReduce3(float& a, float& b, float& c) {
  a = warpReduceSum(a);
  b = warpReduceSum(b);
  c = warpReduceSum(c);
  __shared__ float red[12];
  int w = threadIdx.x >> 6, lane = threadIdx.x & 63;
  if (lane == 0) { red[w] = a; red[4 + w] = b; red[8 + w] = c; }
  __syncthreads();
  a = red[0] + red[1] + red[2] + red[3];
  b = red[4] + red[5] + red[6] + red[7];
  c = red[8] + red[9] + red[10] + red[11];
}

// ---------------- f32 tiled GEMM: C[M,N] = rowscale(A) @ B (+bias)(relu)(+=C) ----------------
// A: M x K row-major, B: K x N row-major. M%128==0, N%128==0, K%16==0.

__global__ __launch_bounds__(256) void gemm_f32(
    const float* __restrict__ A, const float* __restrict__ B, float* __restrict__ C,
    int M, int Nn, int K,
    const float* __restrict__ rowscale, const float* __restrict__ bias,
    int relu, int accum)
{
  __shared__ float As[16][128];   // As[k][m] (A tile transposed)
  __shared__ float Bs[16][128];   // Bs[k][n]
  const int tid = threadIdx.x;
  const int bm = blockIdx.y * 128;
  const int bn = blockIdx.x * 128;
  const int tx = tid & 15;
  const int ty = tid >> 4;

  float acc[8][8];
#pragma unroll
  for (int i = 0; i < 8; ++i)
#pragma unroll
    for (int j = 0; j < 8; ++j) acc[i][j] = 0.f;

  for (int kt = 0; kt < K; kt += 16) {
#pragma unroll
    for (int l = 0; l < 2; ++l) {
      int lid = tid + l * 256;
      // A: 128 rows x 16 k, load float4 along k, store transposed
      int r  = lid >> 2;
      int kq = (lid & 3) * 4;
      float4 va = *(const float4*)(A + (size_t)(bm + r) * K + (kt + kq));
      As[kq + 0][r] = va.x; As[kq + 1][r] = va.y; As[kq + 2][r] = va.z; As[kq + 3][r] = va.w;
      // B: 16 k x 128 n, direct float4
      int kr = lid >> 5;
      int nq = (lid & 31) * 4;
      *(float4*)&Bs[kr][nq] = *(const float4*)(B + (size_t)(kt + kr) * Nn + (bn + nq));
    }
    __syncthreads();
#pragma unroll
    for (int kk = 0; kk < 16; ++kk) {
      float4 a0 = *(const float4*)&As[kk][ty * 4];
      float4 a1 = *(const float4*)&As[kk][64 + ty * 4];
      float4 b0 = *(const float4*)&Bs[kk][tx * 4];
      float4 b1 = *(const float4*)&Bs[kk][64 + tx * 4];
      float av[8] = {a0.x, a0.y, a0.z, a0.w, a1.x, a1.y, a1.z, a1.w};
      float bv[8] = {b0.x, b0.y, b0.z, b0.w, b1.x, b1.y, b1.z, b1.w};
#pragma unroll
      for (int i = 0; i < 8; ++i)
#pragma unroll
        for (int j = 0; j < 8; ++j) acc[i][j] += av[i] * bv[j];
    }
    __syncthreads();
  }

#pragma unroll
  for (int i = 0; i < 8; ++i) {
    int m = bm + ((i < 4) ? (ty * 4 + i) : (64 + ty * 4 + i - 4));
    float rs = rowscale ? rowscale[m] : 1.f;
#pragma unroll
    for (int jh = 0; jh < 2; ++jh) {
      int n0 = bn + jh * 64 + tx * 4;
      float4 v;
      float* vp = &v.x;
#pragma unroll
      for (int j = 0; j < 4; ++j) {
        float t = acc[i][jh * 4 + j] * rs;
        if (bias) t += bias[n0 + j];
        if (relu) t = fmaxf(t, 0.f);
        vp[j] = t;
      }
      float* cp = C + (size_t)m * Nn + n0;
      if (accum) {
        float4 old = *(const float4*)cp;
        v.x += old.x; v.y += old.y; v.z += old.z; v.w += old.w;
      }
      *(float4*)cp = v;
    }
  }
}

// ---------------- node gate: sig[n] = sigmoid(x[n,:]·att_w + att_b) ----------------

__global__ __launch_bounds__(256) void sig_kernel(
    const float* __restrict__ x, const float* __restrict__ att_w,
    const float* __restrict__ att_b, float* __restrict__ sig)
{
  int row  = blockIdx.x * 4 + (threadIdx.x >> 6);
  int lane = threadIdx.x & 63;
  const float4* xr = (const float4*)(x + (size_t)row * DIN);
  const float4* wr = (const float4*)att_w;
  float acc = 0.f;
#pragma unroll
  for (int k = 0; k < DIN / 4 / 64; ++k) {   // 5 iters
    float4 a = xr[lane + k * 64];
    float4 w = wr[lane + k * 64];
    acc += a.x * w.x + a.y * w.y + a.z * w.z + a.w * w.w;
  }
  acc = warpReduceSum(acc);
  if (lane == 0) sig[row] = 1.f / (1.f + expf(-(acc + att_b[0])));
}

// ---------------- GCN tridiagonal aggregate + bias + LN -> out ----------------

__device__ __forceinline__ float dinv_local(int j) {
  return rsqrtf((j == 0 || j == S - 1) ? 3.f : 5.f);
}

__global__ __launch_bounds__(256) void gcnln_kernel(
    const float* __restrict__ h, const float* __restrict__ gcn_b,
    const float* __restrict__ g, const float* __restrict__ be, float* __restrict__ out)
{
  int n = blockIdx.x;
  int i = n % S;
  int tid = threadIdx.x;
  float di = dinv_local(i);
  float wc = di * di;
  float wl = (i > 0)     ? 2.f * di * dinv_local(i - 1) : 0.f;
  float wr = (i < S - 1) ? 2.f * di * dinv_local(i + 1) : 0.f;
  const float* hc = h + (size_t)n * DOUT;
  float vals[4];
  float s = 0.f, sq = 0.f;
#pragma unroll
  for (int q = 0; q < 4; ++q) {
    int d = q * 256 + tid;
    float v = wc * hc[d];
    if (i > 0)     v += wl * hc[d - DOUT];
    if (i < S - 1) v += wr * hc[d + DOUT];
    v += gcn_b[d];
    vals[q] = v;
    s += v; sq += v * v;
  }
  blockReduce2(s, sq);
  float mu = s * (1.f / DOUT);
  float var = sq * (1.f / DOUT) - mu * mu;
  float rstd = rsqrtf(var + 1e-5f);
  float* o = out + (size_t)n * DOUT;
#pragma unroll
  for (int q = 0; q < 4; ++q) {
    int d = q * 256 + tid;
    o[d] = (vals[q] - mu) * rstd * g[d] + be[d];
  }
}

// ---------------- GAT attention logits: al_s/al_d per (node, head) ----------------

__global__ __launch_bounds__(256) void al_kernel(
    const float* __restrict__ h, const float* __restrict__ as_,
    const float* __restrict__ ad_, float* __restrict__ als, float* __restrict__ ald)
{
  int n = blockIdx.x;
  int w = threadIdx.x >> 6;      // head
  int lane = threadIdx.x & 63;
  const float4* hr = (const float4*)(h + (size_t)n * DOUT + w * HC);
  const float4* s4 = (const float4*)(as_ + w * HC);
  const float4* d4 = (const float4*)(ad_ + w * HC);
  float4 hv = hr[lane];
  float4 sv = s4[lane];
  float4 dv = d4[lane];
  float a = hv.x * sv.x + hv.y * sv.y + hv.z * sv.z + hv.w * sv.w;
  float b = hv.x * dv.x + hv.y * dv.y + hv.z * dv.z + hv.w * dv.w;
  a = warpReduceSum(a);
  b = warpReduceSum(b);
  if (lane == 0) {
    als[(size_t)n * HEADS + w] = a;
    ald[(size_t)n * HEADS + w] = b;
  }
}

// ---------------- GAT per-target softmax aggregate + bias + LN -> out ----------------

__global__ __launch_bounds__(256) void gat_kernel(
    const float* __restrict__ h, const float* __restrict__ als, const float* __restrict__ ald,
    const float* __restrict__ gat_b, const float* __restrict__ g, const float* __restrict__ be,
    float* __restrict__ out)
{
  int n = blockIdx.x;
  int b = n / S, t = n % S;
  int lo  = (t >= 39) ? 39 : (t / 13) * 13;
  int cnt = (t >= 39) ? 2 : 13;
  __shared__ float alpha[HEADS][16];
  int tid = threadIdx.x;
  if (tid < HEADS) {
    int hd = tid;
    float myald = ald[(size_t)n * HEADS + hd];
    float m = -1e30f;
    for (int si = 0; si < cnt; ++si) {
      float v = als[(size_t)(b * S + lo + si) * HEADS + hd] + myald;
      v = (v > 0.f) ? v : 0.2f * v;
      m = fmaxf(m, v);
    }
    float den = 0.f;
    for (int si = 0; si < cnt; ++si) {
      float v = als[(size_t)(b * S + lo + si) * HEADS + hd] + myald;
      v = (v > 0.f) ? v : 0.2f * v;
      float e = expf(v - m) * (((lo + si) == t) ? 1.f : 2.f);   // duplicate edges -> weight 2
      alpha[hd][si] = e;
      den += e;
    }
    float inv = 1.f / den;
    for (int si = 0; si < cnt; ++si) alpha[hd][si] *= inv;
  }
  __syncthreads();
  const float* hb = h + (size_t)(b * S + lo) * DOUT;
  float vals[4];
  float s = 0.f, sq = 0.f;
#pragma unroll
  for (int q = 0; q < 4; ++q) {       // head index == q for d = q*256+tid
    int d = q * 256 + tid;
    float accv = 0.f;
    for (int si = 0; si < cnt; ++si)
      accv += alpha[q][si] * hb[(size_t)si * DOUT + d];
    accv += gat_b[d];
    vals[q] = accv;
    s += accv; sq += accv * accv;
  }
  blockReduce2(s, sq);
  float mu = s * (1.f / DOUT);
  float var = sq * (1.f / DOUT) - mu * mu;
  float rstd = rsqrtf(var + 1e-5f);
  float* o = out + (size_t)n * DOUT;
#pragma unroll
  for (int q = 0; q < 4; ++q) {
    int d = q * 256 + tid;
    o[d] = (vals[q] - mu) * rstd * g[d] + be[d];
  }
}

// ---------------- propagation weights: pw = softmax(fp1 @ w2 + b2) over S ----------------

__global__ __launch_bounds__(64) void pw_kernel(
    const float* __restrict__ fp1, const float* __restrict__ w2,
    const float* __restrict__ b2, float* __restrict__ pw)
{
  __shared__ float row[512];
  int n = blockIdx.x;
  int lane = threadIdx.x;
  const float* fr = fp1 + (size_t)n * 512;
#pragma unroll
  for (int k = 0; k < 8; ++k) row[lane + k * 64] = fr[lane + k * 64];
  __syncthreads();
  float acc = -1e30f;
  if (lane < S) {
    acc = b2[lane];
    for (int k = 0; k < 512; ++k) acc += row[k] * w2[k * S + lane];
  }
  float m = acc;
#pragma unroll
  for (int off = 32; off; off >>= 1) m = fmaxf(m, __shfl_xor(m, off));
  float e = (lane < S) ? expf(acc - m) : 0.f;
  float sum = e;
#pragma unroll
  for (int off = 32; off; off >>= 1) sum += __shfl_xor(sum, off);
  if (lane < S) pw[(size_t)n * S + lane] = e / sum;
}

// ---------------- sage_in = pw @ x (per batch) and prefix-mean agg ----------------

__global__ __launch_bounds__(256) void sagein_kernel(
    const float* __restrict__ pw, const float* __restrict__ x,
    float* __restrict__ sin_, float* __restrict__ agg)
{
  int b = blockIdx.y;
  int d0 = blockIdx.x * 256;
  int tid = threadIdx.x;
  __shared__ float pws[S * S];
  for (int i = tid; i < S * S; i += 256) pws[i] = pw[(size_t)b * S * S + i];
  __syncthreads();
  float xreg[S];
  const float* xb = x + (size_t)b * S * DIN + d0 + tid;
#pragma unroll
  for (int j = 0; j < S; ++j) xreg[j] = xb[(size_t)j * DIN];
  float prefix = 0.f;
  for (int i = 0; i < S; ++i) {
    float v = 0.f;
#pragma unroll
    for (int j = 0; j < S; ++j) v += pws[i * S + j] * xreg[j];
    size_t idx = (size_t)(b * S + i) * DIN + d0 + tid;
    sin_[idx] = v;
    agg[idx] = (i > 0) ? (prefix / (float)i) : 0.f;   // sum_{s<i} / max(i,1)
    prefix += v;
  }
}

// ---------------- plain LN -> out ----------------

__global__ __launch_bounds__(256) void ln_kernel(
    const float* __restrict__ h, const float* __restrict__ g,
    const float* __restrict__ be, float* __restrict__ out)
{
  int n = blockIdx.x;
  int tid = threadIdx.x;
  const float* hr = h + (size_t)n * DOUT;
  float vals[4];
  float s = 0.f, sq = 0.f;
#pragma unroll
  for (int q = 0; q < 4; ++q) {
    int d = q * 256 + tid;
    float v = hr[d];
    vals[q] = v;
    s += v; sq += v * v;
  }
  blockReduce2(s, sq);
  float mu = s * (1.f / DOUT);
  float var = sq * (1.f / DOUT) - mu * mu;
  float rstd = rsqrtf(var + 1e-5f);
  float* o = out + (size_t)n * DOUT;
#pragma unroll
  for (int q = 0; q < 4; ++q) {
    int d = q * 256 + tid;
    o[d] = (vals[q] - mu) * rstd * g[d] + be[d];
  }
}

// ---------------- gated mixing: total -> out2 (in place over sage) ----------------

__global__ __launch_bounds__(256) void gate_kernel(
    float* __restrict__ out, const float* __restrict__ gw,
    const float* __restrict__ gb, int N)
{
  size_t OUT = (size_t)N * DOUT;
  int n = blockIdx.x;
  int tid = threadIdx.x;
  const float* shp = out + (size_t)n * DOUT;
  const float* gap = shp + OUT;
  const float* sap = shp + 2 * OUT;
  float sh[4], ga[4], sa[4];
  float p0 = 0.f, p1 = 0.f, p2 = 0.f;
#pragma unroll
  for (int q = 0; q < 4; ++q) {
    int d = q * 256 + tid;
    sh[q] = shp[d]; ga[q] = gap[d]; sa[q] = sap[d];
    const float* w0 = gw + (size_t)d * 3;
    const float* w1 = gw + (size_t)(DOUT + d) * 3;
    const float* w2 = gw + (size_t)(2 * DOUT + d) * 3;
    p0 += sh[q] * w0[0] + ga[q] * w1[0] + sa[q] * w2[0];
    p1 += sh[q] * w0[1] + ga[q] * w1[1] + sa[q] * w2[1];
    p2 += sh[q] * w0[2] + ga[q] * w1[2] + sa[q] * w2[2];
  }
  blockReduce3(p0, p1, p2);
  p0 += gb[0]; p1 += gb[1]; p2 += gb[2];
  float m = fmaxf(p0, fmaxf(p1, p2));
  float e0 = expf(p0 - m), e1 = expf(p1 - m), e2 = expf(p2 - m);
  float inv = 1.f / (e0 + e1 + e2);
  float g0 = e0 * inv, g1 = e1 * inv, g2 = e2 * inv;
  float* op = out + 2 * OUT + (size_t)n * DOUT;
#pragma unroll
  for (int q = 0; q < 4; ++q) {
    int d = q * 256 + tid;
    op[d] = g0 * sh[q] + g1 * ga[q] + g2 * sa[q];
  }
}

// ---------------- launch ----------------

extern "C" void kernel_launch(void* const* d_in, const int* in_sizes, int n_in,
                              void* d_out, int out_size, void* d_ws, size_t ws_size,
                              hipStream_t stream) {
  const float* x       = (const float*)d_in[0];
  const float* att_w   = (const float*)d_in[1];
  const float* att_b   = (const float*)d_in[2];
  const float* gcn_w   = (const float*)d_in[3];
  const float* gcn_b   = (const float*)d_in[4];
  const float* sn_g    = (const float*)d_in[5];
  const float* sn_b    = (const float*)d_in[6];
  const float* gat_w   = (const float*)d_in[7];
  const float* gat_as  = (const float*)d_in[8];
  const float* gat_ad  = (const float*)d_in[9];
  const float* gat_b   = (const float*)d_in[10];
  const float* mn_g    = (const float*)d_in[11];
  const float* mn_b    = (const float*)d_in[12];
  const float* sage_wl = (const float*)d_in[13];
  const float* sage_bl = (const float*)d_in[14];
  const float* sage_wr = (const float*)d_in[15];
  const float* fp_w1   = (const float*)d_in[16];
  const float* fp_b1   = (const float*)d_in[17];
  const float* fp_w2   = (const float*)d_in[18];
  const float* fp_b2   = (const float*)d_in[19];
  const float* dn_g    = (const float*)d_in[20];
  const float* dn_b    = (const float*)d_in[21];
  const float* gate_w  = (const float*)d_in[22];
  const float* gate_b  = (const float*)d_in[23];

  const int B = in_sizes[0] / (S * DIN);   // 512
  const int N = B * S;                     // 20992 (= 164 * 128)
  float* out = (float*)d_out;

  char* ws = (char*)d_ws;
  size_t off = 0;
  auto alloc = [&](size_t bytes) { size_t p = off; off += (bytes + 255) & ~(size_t)255; return p; };
  float* sig  = (float*)(ws + alloc((size_t)N * 4));
  float* hbuf = (float*)(ws + alloc((size_t)N * DOUT * 4));
  float* sin_ = (float*)(ws + alloc((size_t)N * DIN * 4));
  float* agg  = (float*)(ws + alloc((size_t)N * DIN * 4));
  float* pw   = (float*)(ws + alloc((size_t)N * S * 4));
  float* als  = (float*)(ws + alloc((size_t)N * HEADS * 4));
  float* ald  = (float*)(ws + alloc((size_t)N * HEADS * 4));
  float* fp1  = sin_;   // alias: fp1 (N x 512) is dead before sin_ is written

  dim3 blk(256);
  dim3 gemm_grid_1024(DOUT / 128, N / 128);
  dim3 gemm_grid_512(512 / 128, N / 128);

  // shallow branch: sig gate (folded to epilogue rowscale) -> GCN GEMM -> stencil+LN
  sig_kernel<<<N / 4, blk, 0, stream>>>(x, att_w, att_b, sig);
  gemm_f32<<<gemm_grid_1024, blk, 0, stream>>>(x, gcn_w, hbuf, N, DOUT, DIN, sig, nullptr, 0, 0);
  gcnln_kernel<<<N, blk, 0, stream>>>(hbuf, gcn_b, sn_g, sn_b, out);

  // medium branch: GAT GEMM -> attention logits -> block softmax aggregate + LN
  gemm_f32<<<gemm_grid_1024, blk, 0, stream>>>(x, gat_w, hbuf, N, DOUT, DIN, nullptr, nullptr, 0, 0);
  al_kernel<<<N, blk, 0, stream>>>(hbuf, gat_as, gat_ad, als, ald);
  gat_kernel<<<N, blk, 0, stream>>>(hbuf, als, ald, gat_b, mn_g, mn_b, out + (size_t)N * DOUT);

  // deep branch: fp MLP -> softmax pw -> sage_in/agg -> two GEMMs -> LN
  gemm_f32<<<gemm_grid_512, blk, 0, stream>>>(x, fp_w1, fp1, N, 512, DIN, nullptr, fp_b1, 1, 0);
  pw_kernel<<<N, dim3(64), 0, stream>>>(fp1, fp_w2, fp_b2, pw);
  sagein_kernel<<<dim3(DIN / 256, B), blk, 0, stream>>>(pw, x, sin_, agg);
  gemm_f32<<<gemm_grid_1024, blk, 0, stream>>>(sin_, sage_wr, hbuf, N, DOUT, DIN, nullptr, sage_bl, 0, 0);
  gemm_f32<<<gemm_grid_1024, blk, 0, stream>>>(agg, sage_wl, hbuf, N, DOUT, DIN, nullptr, nullptr, 0, 1);
  ln_kernel<<<N, blk, 0, stream>>>(hbuf, dn_g, dn_b, out + 2 * (size_t)N * DOUT);

  // gated mixing (reads out0/out1/out2-sage, writes total into out2)
  gate_kernel<<<N, blk, 0, stream>>>(out, gate_w, gate_b, N);
}

// Round 2
// 1003.477 us; speedup vs baseline: 3.5506x; 3.5506x over previous
//
#include <hip/hip_runtime.h>
#include <math.h>

static constexpr int S    = 41;
static constexpr int DIN  = 1280;
static constexpr int DOUT = 1024;
static constexpr int HEADS = 4;
static constexpr int HC   = 256;

typedef __attribute__((ext_vector_type(4))) float f32x4;
typedef __attribute__((ext_vector_type(8))) short short8;

__device__ __forceinline__ ushort f2bf(float f) {
  uint u = __float_as_uint(f);
  uint r = u + 0x7fffu + ((u >> 16) & 1u);   // RNE
  return (ushort)(r >> 16);
}

__device__ __forceinline__ void gload16(const ushort* g, ushort* l) {
  __builtin_amdgcn_global_load_lds((const __attribute__((address_space(1))) void*)g,
                                   (__attribute__((address_space(3))) void*)l, 16, 0, 0);
}

// ---------------- reduction helpers ----------------

__device__ __forceinline__ float warpReduceSum(float v) {
#pragma unroll
  for (int off = 32; off; off >>= 1) v += __shfl_down(v, off);
  return v;
}

__device__ __forceinline__ void blockReduce2(float& a, float& b) {
  a = warpReduceSum(a);
  b = warpReduceSum(b);
  __shared__ float red[8];
  int w = threadIdx.x >> 6, lane = threadIdx.x & 63;
  if (lane == 0) { red[w] = a; red[4 + w] = b; }
  __syncthreads();
  a = red[0] + red[1] + red[2] + red[3];
  b = red[4] + red[5] + red[6] + red[7];
}

__device__ __forceinline__ void blockReduce3(float& a, float& b, float& c) {
  a = warpReduceSum(a);
  b = warpReduceSum(b);
  c = warpReduceSum(c);
  __shared__ float red[12];
  int w = threadIdx.x >> 6, lane = threadIdx.x & 63;
  if (lane == 0) { red[w] = a; red[4 + w] = b; red[8 + w] = c; }
  __syncthreads();
  a = red[0] + red[1] + red[2] + red[3];
  b = red[4] + red[5] + red[6] + red[7];
  c = red[8] + red[9] + red[10] + red[11];
}

// ---------------- converts ----------------

__global__ __launch_bounds__(256) void cvtx_kernel(const float4* __restrict__ x,
                                                   ushort4* __restrict__ xb) {
  size_t i = (size_t)blockIdx.x * 256 + threadIdx.x;
  float4 v = x[i];
  ushort4 o;
  o.x = f2bf(v.x); o.y = f2bf(v.y); o.z = f2bf(v.z); o.w = f2bf(v.w);
  xb[i] = o;
}

// out[n][k] = bf16(W[k][n]); out row-stride = ostride, rows offset by obase rows.
__global__ __launch_bounds__(256) void wcvt_kernel(const float* __restrict__ W,
                                                   ushort* __restrict__ out,
                                                   int K, int N, int ostride, int koff) {
  __shared__ float t[32][33];
  int n0 = blockIdx.x * 32, k0 = blockIdx.y * 32;
  int tx = threadIdx.x & 31, ty = threadIdx.x >> 5;   // 32 x 8
#pragma unroll
  for (int r = 0; r < 4; ++r) {
    int k = ty + r * 8;
    t[k][tx] = W[(size_t)(k0 + k) * N + n0 + tx];
  }
  __syncthreads();
#pragma unroll
  for (int r = 0; r < 4; ++r) {
    int nn = ty + r * 8;
    out[(size_t)(n0 + nn) * ostride + koff + k0 + tx] = f2bf(t[tx][nn]);
  }
}

// ---------------- bf16 MFMA GEMM: C = A[M,K] @ Bt[N,K]^T, column-block epilogues ----------------

struct Epi {
  float* dst0; float* dst1; float* dst2;
  const float* bias0; const float* bias1; const float* bias2;
  const float* rs0;            // rowscale, branch 0 only
  int n1, n2;                  // col boundaries between branches
  int ld0, ld1, ld2;
  int relu2;                   // relu, branch 2 only
};

__global__ __launch_bounds__(256) void gemm_bf16(
    const ushort* __restrict__ A, const ushort* __restrict__ Bt, int K, Epi e)
{
  __shared__ __align__(16) ushort As[128 * 32];
  __shared__ __align__(16) ushort Bs[128 * 32];

  const int tid  = threadIdx.x;
  const int w    = tid >> 6;
  const int lane = tid & 63;
  const int l16  = lane & 15;
  const int l4   = lane >> 4;
  const int bm   = blockIdx.y * 128;
  const int bn   = blockIdx.x * 128;
  const int m0   = (w >> 1) * 64;
  const int n0   = (w & 1) * 64;

  const int srow = w * 32 + (lane >> 2);
  const int scol = (lane & 3) * 8;

  f32x4 acc[4][4];
#pragma unroll
  for (int i = 0; i < 4; ++i)
#pragma unroll
    for (int j = 0; j < 4; ++j) acc[i][j] = (f32x4)0.f;

  const ushort* pA0 = A  + (size_t)(bm + srow) * K + scol;
  const ushort* pA1 = A  + (size_t)(bm + srow + 16) * K + scol;
  const ushort* pB0 = Bt + (size_t)(bn + srow) * K + scol;
  const ushort* pB1 = Bt + (size_t)(bn + srow + 16) * K + scol;
  ushort* lA0 = &As[w * 1024];
  ushort* lA1 = &As[w * 1024 + 512];
  ushort* lB0 = &Bs[w * 1024];
  ushort* lB1 = &Bs[w * 1024 + 512];

  for (int kt = 0; kt < K; kt += 32) {
    gload16(pA0 + kt, lA0);
    gload16(pA1 + kt, lA1);
    gload16(pB0 + kt, lB0);
    gload16(pB1 + kt, lB1);
    __syncthreads();

    short8 a[4], b[4];
#pragma unroll
    for (int i = 0; i < 4; ++i)
      a[i] = *reinterpret_cast<const short8*>(&As[(m0 + i * 16 + l16) * 32 + l4 * 8]);
#pragma unroll
    for (int j = 0; j < 4; ++j)
      b[j] = *reinterpret_cast<const short8*>(&Bs[(n0 + j * 16 + l16) * 32 + l4 * 8]);
#pragma unroll
    for (int i = 0; i < 4; ++i)
#pragma unroll
      for (int j = 0; j < 4; ++j)
        acc[i][j] = __builtin_amdgcn_mfma_f32_16x16x32_bf16(a[i], b[j], acc[i][j], 0, 0, 0);
    __syncthreads();
  }

  // epilogue: per-block column branch
  float* dst; const float* bias; const float* rs = nullptr; int ldc, cb, relu = 0;
  if (bn < e.n1)      { dst = e.dst0; ldc = e.ld0; cb = bn;        bias = e.bias0; rs = e.rs0; }
  else if (bn < e.n2) { dst = e.dst1; ldc = e.ld1; cb = bn - e.n1; bias = e.bias1; }
  else                { dst = e.dst2; ldc = e.ld2; cb = bn - e.n2; bias = e.bias2; relu = e.relu2; }

#pragma unroll
  for (int i = 0; i < 4; ++i) {
    int mbase = bm + m0 + i * 16 + l4 * 4;
    float rsv[4];
#pragma unroll
    for (int r = 0; r < 4; ++r) rsv[r] = rs ? rs[mbase + r] : 1.f;
#pragma unroll
    for (int j = 0; j < 4; ++j) {
      int col = cb + n0 + j * 16 + l16;
      float bv = bias ? bias[col] : 0.f;
#pragma unroll
      for (int r = 0; r < 4; ++r) {
        float t = acc[i][j][r] * rsv[r] + bv;
        if (relu) t = fmaxf(t, 0.f);
        dst[(size_t)(mbase + r) * ldc + col] = t;
      }
    }
  }
}

// ---------------- node gate: sig[n] = sigmoid(x[n,:]·att_w + att_b) ----------------

__global__ __launch_bounds__(256) void sig_kernel(
    const float* __restrict__ x, const float* __restrict__ att_w,
    const float* __restrict__ att_b, float* __restrict__ sig)
{
  int row  = blockIdx.x * 4 + (threadIdx.x >> 6);
  int lane = threadIdx.x & 63;
  const float4* xr = (const float4*)(x + (size_t)row * DIN);
  const float4* wr = (const float4*)att_w;
  float acc = 0.f;
#pragma unroll
  for (int k = 0; k < DIN / 4 / 64; ++k) {
    float4 a = xr[lane + k * 64];
    float4 w = wr[lane + k * 64];
    acc += a.x * w.x + a.y * w.y + a.z * w.z + a.w * w.w;
  }
  acc = warpReduceSum(acc);
  if (lane == 0) sig[row] = 1.f / (1.f + expf(-(acc + att_b[0])));
}

// ---------------- GCN tridiagonal aggregate + bias + LN -> out ----------------

__device__ __forceinline__ float dinv_local(int j) {
  return rsqrtf((j == 0 || j == S - 1) ? 3.f : 5.f);
}

__global__ __launch_bounds__(256) void gcnln_kernel(
    const float* __restrict__ h, const float* __restrict__ gcn_b,
    const float* __restrict__ g, const float* __restrict__ be, float* __restrict__ out)
{
  int n = blockIdx.x;
  int i = n % S;
  int tid = threadIdx.x;
  float di = dinv_local(i);
  float wc = di * di;
  float wl = (i > 0)     ? 2.f * di * dinv_local(i - 1) : 0.f;
  float wr = (i < S - 1) ? 2.f * di * dinv_local(i + 1) : 0.f;
  const float* hc = h + (size_t)n * DOUT;
  float vals[4];
  float s = 0.f, sq = 0.f;
#pragma unroll
  for (int q = 0; q < 4; ++q) {
    int d = q * 256 + tid;
    float v = wc * hc[d];
    if (i > 0)     v += wl * hc[d - DOUT];
    if (i < S - 1) v += wr * hc[d + DOUT];
    v += gcn_b[d];
    vals[q] = v;
    s += v; sq += v * v;
  }
  blockReduce2(s, sq);
  float mu = s * (1.f / DOUT);
  float var = sq * (1.f / DOUT) - mu * mu;
  float rstd = rsqrtf(var + 1e-5f);
  float* o = out + (size_t)n * DOUT;
#pragma unroll
  for (int q = 0; q < 4; ++q) {
    int d = q * 256 + tid;
    o[d] = (vals[q] - mu) * rstd * g[d] + be[d];
  }
}

// ---------------- GAT attention logits ----------------

__global__ __launch_bounds__(256) void al_kernel(
    const float* __restrict__ h, const float* __restrict__ as_,
    const float* __restrict__ ad_, float* __restrict__ als, float* __restrict__ ald)
{
  int n = blockIdx.x;
  int w = threadIdx.x >> 6;
  int lane = threadIdx.x & 63;
  const float4* hr = (const float4*)(h + (size_t)n * DOUT + w * HC);
  const float4* s4 = (const float4*)(as_ + w * HC);
  const float4* d4 = (const float4*)(ad_ + w * HC);
  float4 hv = hr[lane];
  float4 sv = s4[lane];
  float4 dv = d4[lane];
  float a = hv.x * sv.x + hv.y * sv.y + hv.z * sv.z + hv.w * sv.w;
  float b = hv.x * dv.x + hv.y * dv.y + hv.z * dv.z + hv.w * dv.w;
  a = warpReduceSum(a);
  b = warpReduceSum(b);
  if (lane == 0) {
    als[(size_t)n * HEADS + w] = a;
    ald[(size_t)n * HEADS + w] = b;
  }
}

// ---------------- GAT per-target softmax aggregate + bias + LN -> out ----------------

__global__ __launch_bounds__(256) void gat_kernel(
    const float* __restrict__ h, const float* __restrict__ als, const float* __restrict__ ald,
    const float* __restrict__ gat_b, const float* __restrict__ g, const float* __restrict__ be,
    float* __restrict__ out)
{
  int n = blockIdx.x;
  int b = n / S, t = n % S;
  int lo  = (t >= 39) ? 39 : (t / 13) * 13;
  int cnt = (t >= 39) ? 2 : 13;
  __shared__ float alpha[HEADS][16];
  int tid = threadIdx.x;
  if (tid < HEADS) {
    int hd = tid;
    float myald = ald[(size_t)n * HEADS + hd];
    float m = -1e30f;
    for (int si = 0; si < cnt; ++si) {
      float v = als[(size_t)(b * S + lo + si) * HEADS + hd] + myald;
      v = (v > 0.f) ? v : 0.2f * v;
      m = fmaxf(m, v);
    }
    float den = 0.f;
    for (int si = 0; si < cnt; ++si) {
      float v = als[(size_t)(b * S + lo + si) * HEADS + hd] + myald;
      v = (v > 0.f) ? v : 0.2f * v;
      float ev = expf(v - m) * (((lo + si) == t) ? 1.f : 2.f);
      alpha[hd][si] = ev;
      den += ev;
    }
    float inv = 1.f / den;
    for (int si = 0; si < cnt; ++si) alpha[hd][si] *= inv;
  }
  __syncthreads();
  const float* hb = h + (size_t)(b * S + lo) * DOUT;
  float vals[4];
  float s = 0.f, sq = 0.f;
#pragma unroll
  for (int q = 0; q < 4; ++q) {
    int d = q * 256 + tid;
    float accv = 0.f;
    for (int si = 0; si < cnt; ++si)
      accv += alpha[q][si] * hb[(size_t)si * DOUT + d];
    accv += gat_b[d];
    vals[q] = accv;
    s += accv; sq += accv * accv;
  }
  blockReduce2(s, sq);
  float mu = s * (1.f / DOUT);
  float var = sq * (1.f / DOUT) - mu * mu;
  float rstd = rsqrtf(var + 1e-5f);
  float* o = out + (size_t)n * DOUT;
#pragma unroll
  for (int q = 0; q < 4; ++q) {
    int d = q * 256 + tid;
    o[d] = (vals[q] - mu) * rstd * g[d] + be[d];
  }
}

// ---------------- propagation weights: pw = softmax(fp1 @ w2 + b2) ----------------

__global__ __launch_bounds__(64) void pw_kernel(
    const float* __restrict__ fp1, const float* __restrict__ w2,
    const float* __restrict__ b2, float* __restrict__ pw)
{
  __shared__ float row[512];
  int n = blockIdx.x;
  int lane = threadIdx.x;
  const float* fr = fp1 + (size_t)n * 512;
#pragma unroll
  for (int k = 0; k < 8; ++k) row[lane + k * 64] = fr[lane + k * 64];
  __syncthreads();
  float acc = -1e30f;
  if (lane < S) {
    acc = b2[lane];
    for (int k = 0; k < 512; ++k) acc += row[k] * w2[k * S + lane];
  }
  float m = acc;
#pragma unroll
  for (int off = 32; off; off >>= 1) m = fmaxf(m, __shfl_xor(m, off));
  float e = (lane < S) ? expf(acc - m) : 0.f;
  float sum = e;
#pragma unroll
  for (int off = 32; off; off >>= 1) sum += __shfl_xor(sum, off);
  if (lane < S) pw[(size_t)n * S + lane] = e / sum;
}

// ---------------- sage_in/agg -> interleaved bf16 rows [sin | agg] ----------------

__global__ __launch_bounds__(256) void sagein_kernel(
    const float* __restrict__ pw, const float* __restrict__ x,
    ushort* __restrict__ sa)
{
  int b = blockIdx.y;
  int d0 = blockIdx.x * 256;
  int tid = threadIdx.x;
  __shared__ float pws[S * S];
  for (int i = tid; i < S * S; i += 256) pws[i] = pw[(size_t)b * S * S + i];
  __syncthreads();
  float xreg[S];
  const float* xb = x + (size_t)b * S * DIN + d0 + tid;
#pragma unroll
  for (int j = 0; j < S; ++j) xreg[j] = xb[(size_t)j * DIN];
  float prefix = 0.f;
  for (int i = 0; i < S; ++i) {
    float v = 0.f;
#pragma unroll
    for (int j = 0; j < S; ++j) v += pws[i * S + j] * xreg[j];
    size_t base = (size_t)(b * S + i) * (2 * DIN) + d0 + tid;
    sa[base] = f2bf(v);
    sa[base + DIN] = f2bf((i > 0) ? (prefix / (float)i) : 0.f);
    prefix += v;
  }
}

// ---------------- plain LN -> out ----------------

__global__ __launch_bounds__(256) void ln_kernel(
    const float* __restrict__ h, const float* __restrict__ g,
    const float* __restrict__ be, float* __restrict__ out)
{
  int n = blockIdx.x;
  int tid = threadIdx.x;
  const float* hr = h + (size_t)n * DOUT;
  float vals[4];
  float s = 0.f, sq = 0.f;
#pragma unroll
  for (int q = 0; q < 4; ++q) {
    int d = q * 256 + tid;
    float v = hr[d];
    vals[q] = v;
    s += v; sq += v * v;
  }
  blockReduce2(s, sq);
  float mu = s * (1.f / DOUT);
  float var = sq * (1.f / DOUT) - mu * mu;
  float rstd = rsqrtf(var + 1e-5f);
  float* o = out + (size_t)n * DOUT;
#pragma unroll
  for (int q = 0; q < 4; ++q) {
    int d = q * 256 + tid;
    o[d] = (vals[q] - mu) * rstd * g[d] + be[d];
  }
}

// ---------------- gated mixing ----------------

__global__ __launch_bounds__(256) void gate_kernel(
    float* __restrict__ out, const float* __restrict__ gw,
    const float* __restrict__ gb, int N)
{
  size_t OUT = (size_t)N * DOUT;
  int n = blockIdx.x;
  int tid = threadIdx.x;
  const float* shp = out + (size_t)n * DOUT;
  const float* gap = shp + OUT;
  const float* sap = shp + 2 * OUT;
  float sh[4], ga[4], sa[4];
  float p0 = 0.f, p1 = 0.f, p2 = 0.f;
#pragma unroll
  for (int q = 0; q < 4; ++q) {
    int d = q * 256 + tid;
    sh[q] = shp[d]; ga[q] = gap[d]; sa[q] = sap[d];
    const float* w0 = gw + (size_t)d * 3;
    const float* w1 = gw + (size_t)(DOUT + d) * 3;
    const float* w2 = gw + (size_t)(2 * DOUT + d) * 3;
    p0 += sh[q] * w0[0] + ga[q] * w1[0] + sa[q] * w2[0];
    p1 += sh[q] * w0[1] + ga[q] * w1[1] + sa[q] * w2[1];
    p2 += sh[q] * w0[2] + ga[q] * w1[2] + sa[q] * w2[2];
  }
  blockReduce3(p0, p1, p2);
  p0 += gb[0]; p1 += gb[1]; p2 += gb[2];
  float m = fmaxf(p0, fmaxf(p1, p2));
  float e0 = expf(p0 - m), e1 = expf(p1 - m), e2 = expf(p2 - m);
  float inv = 1.f / (e0 + e1 + e2);
  float g0 = e0 * inv, g1 = e1 * inv, g2 = e2 * inv;
  float* op = out + 2 * OUT + (size_t)n * DOUT;
#pragma unroll
  for (int q = 0; q < 4; ++q) {
    int d = q * 256 + tid;
    op[d] = g0 * sh[q] + g1 * ga[q] + g2 * sa[q];
  }
}

// ---------------- launch ----------------

extern "C" void kernel_launch(void* const* d_in, const int* in_sizes, int n_in,
                              void* d_out, int out_size, void* d_ws, size_t ws_size,
                              hipStream_t stream) {
  const float* x       = (const float*)d_in[0];
  const float* att_w   = (const float*)d_in[1];
  const float* att_b   = (const float*)d_in[2];
  const float* gcn_w   = (const float*)d_in[3];
  const float* gcn_b   = (const float*)d_in[4];
  const float* sn_g    = (const float*)d_in[5];
  const float* sn_b    = (const float*)d_in[6];
  const float* gat_w   = (const float*)d_in[7];
  const float* gat_as  = (const float*)d_in[8];
  const float* gat_ad  = (const float*)d_in[9];
  const float* gat_b   = (const float*)d_in[10];
  const float* mn_g    = (const float*)d_in[11];
  const float* mn_b    = (const float*)d_in[12];
  const float* sage_wl = (const float*)d_in[13];
  const float* sage_bl = (const float*)d_in[14];
  const float* sage_wr = (const float*)d_in[15];
  const float* fp_w1   = (const float*)d_in[16];
  const float* fp_b1   = (const float*)d_in[17];
  const float* fp_w2   = (const float*)d_in[18];
  const float* fp_b2   = (const float*)d_in[19];
  const float* dn_g    = (const float*)d_in[20];
  const float* dn_b    = (const float*)d_in[21];
  const float* gate_w  = (const float*)d_in[22];
  const float* gate_b  = (const float*)d_in[23];

  const int B = in_sizes[0] / (S * DIN);   // 512
  const int N = B * S;                     // 20992 = 164*128
  float* out = (float*)d_out;
  float* gcnh = out + 2 * (size_t)N * DOUT;   // out2 region doubles as gcn-h scratch

  char* ws = (char*)d_ws;
  size_t off = 0;
  auto alloc = [&](size_t bytes) { size_t p = off; off += (bytes + 255) & ~(size_t)255; return p; };
  ushort* xb   = (ushort*)(ws + alloc((size_t)N * DIN * 2));          // 53.7 MB
  ushort* Bt1  = (ushort*)(ws + alloc((size_t)2560 * DIN * 2));       // 6.6 MB
  ushort* Bt2  = (ushort*)(ws + alloc((size_t)DOUT * 2 * DIN * 2));   // 5.2 MB
  float*  Cgat = (float*)(ws + alloc((size_t)N * DOUT * 4));          // 86 MB (also sage hbuf)
  ushort* sa   = (ushort*)(ws + alloc((size_t)N * 2 * DIN * 2));      // 107.5 MB (fp1 aliased below)
  float*  pw   = (float*)(ws + alloc((size_t)N * S * 4));
  float*  sig  = (float*)(ws + alloc((size_t)N * 4));
  float*  als  = (float*)(ws + alloc((size_t)N * HEADS * 4));
  float*  ald  = (float*)(ws + alloc((size_t)N * HEADS * 4));
  float*  fp1  = (float*)sa;          // fp1 (N x 512 f32) dead before sa is written
  float*  hbuf = Cgat;                // sage GEMM output, Cgat dead by then

  dim3 blk(256);

  // conversions
  cvtx_kernel<<<(N * DIN / 4 + 255) / 256, blk, 0, stream>>>((const float4*)x, (ushort4*)xb);
  wcvt_kernel<<<dim3(DOUT / 32, DIN / 32), blk, 0, stream>>>(gcn_w, Bt1, DIN, DOUT, DIN, 0);
  wcvt_kernel<<<dim3(DOUT / 32, DIN / 32), blk, 0, stream>>>(gat_w, Bt1 + (size_t)1024 * DIN, DIN, DOUT, DIN, 0);
  wcvt_kernel<<<dim3(512 / 32, DIN / 32), blk, 0, stream>>>(fp_w1, Bt1 + (size_t)2048 * DIN, DIN, 512, DIN, 0);
  wcvt_kernel<<<dim3(DOUT / 32, DIN / 32), blk, 0, stream>>>(sage_wr, Bt2, DIN, DOUT, 2 * DIN, 0);
  wcvt_kernel<<<dim3(DOUT / 32, DIN / 32), blk, 0, stream>>>(sage_wl, Bt2, DIN, DOUT, 2 * DIN, DIN);

  // sigmoid row gate
  sig_kernel<<<N / 4, blk, 0, stream>>>(x, att_w, att_b, sig);

  // GEMM1: x_bf16 @ [gcn_w | gat_w | fp_w1]  (N=2560)
  Epi e1;
  e1.dst0 = gcnh; e1.dst1 = Cgat; e1.dst2 = fp1;
  e1.bias0 = nullptr; e1.bias1 = nullptr; e1.bias2 = fp_b1;
  e1.rs0 = sig;
  e1.n1 = 1024; e1.n2 = 2048;
  e1.ld0 = DOUT; e1.ld1 = DOUT; e1.ld2 = 512;
  e1.relu2 = 1;
  gemm_bf16<<<dim3(2560 / 128, N / 128), blk, 0, stream>>>(xb, Bt1, DIN, e1);

  // shallow: stencil + LN
  gcnln_kernel<<<N, blk, 0, stream>>>(gcnh, gcn_b, sn_g, sn_b, out);

  // medium: GAT
  al_kernel<<<N, blk, 0, stream>>>(Cgat, gat_as, gat_ad, als, ald);
  gat_kernel<<<N, blk, 0, stream>>>(Cgat, als, ald, gat_b, mn_g, mn_b, out + (size_t)N * DOUT);

  // deep: pw softmax -> sage_in/agg (bf16) -> fused SAGE GEMM (K=2560) -> LN
  pw_kernel<<<N, dim3(64), 0, stream>>>(fp1, fp_w2, fp_b2, pw);
  sagein_kernel<<<dim3(DIN / 256, B), blk, 0, stream>>>(pw, x, sa);

  Epi e2;
  e2.dst0 = hbuf; e2.dst1 = nullptr; e2.dst2 = nullptr;
  e2.bias0 = sage_bl; e2.bias1 = nullptr; e2.bias2 = nullptr;
  e2.rs0 = nullptr;
  e2.n1 = 1 << 30; e2.n2 = 1 << 30;
  e2.ld0 = DOUT; e2.ld1 = DOUT; e2.ld2 = DOUT;
  e2.relu2 = 0;
  gemm_bf16<<<dim3(DOUT / 128, N / 128), blk, 0, stream>>>(sa, Bt2, 2 * DIN, e2);

  ln_kernel<<<N, blk, 0, stream>>>(hbuf, dn_g, dn_b, out + 2 * (size_t)N * DOUT);

  // gated mixing
  gate_kernel<<<N, blk, 0, stream>>>(out, gate_w, gate_b, N);
}

// Round 3
// 764.840 us; speedup vs baseline: 4.6584x; 1.3120x over previous
//
#include <hip/hip_runtime.h>
#include <math.h>

static constexpr int S    = 41;
static constexpr int DIN  = 1280;
static constexpr int DOUT = 1024;
static constexpr int HEADS = 4;
static constexpr int HC   = 256;

typedef __attribute__((ext_vector_type(4))) float f32x4;
typedef __attribute__((ext_vector_type(8))) short short8;

__device__ __forceinline__ ushort f2bf(float f) {
  uint u = __float_as_uint(f);
  uint r = u + 0x7fffu + ((u >> 16) & 1u);   // RNE
  return (ushort)(r >> 16);
}
__device__ __forceinline__ float bf2f(ushort u) {
  return __uint_as_float(((uint)u) << 16);
}

__device__ __forceinline__ void gload16(const ushort* g, ushort* l) {
  __builtin_amdgcn_global_load_lds((const __attribute__((address_space(1))) void*)g,
                                   (__attribute__((address_space(3))) void*)l, 16, 0, 0);
}

// ---------------- reduction helpers ----------------

__device__ __forceinline__ float warpReduceSum(float v) {
#pragma unroll
  for (int off = 32; off; off >>= 1) v += __shfl_down(v, off);
  return v;
}

__device__ __forceinline__ void blockReduce2(float& a, float& b) {
  a = warpReduceSum(a);
  b = warpReduceSum(b);
  __shared__ float red[8];
  int w = threadIdx.x >> 6, lane = threadIdx.x & 63;
  if (lane == 0) { red[w] = a; red[4 + w] = b; }
  __syncthreads();
  a = red[0] + red[1] + red[2] + red[3];
  b = red[4] + red[5] + red[6] + red[7];
}

__device__ __forceinline__ void blockReduce3(float& a, float& b, float& c) {
  a = warpReduceSum(a);
  b = warpReduceSum(b);
  c = warpReduceSum(c);
  __shared__ float red3[12];
  int w = threadIdx.x >> 6, lane = threadIdx.x & 63;
  if (lane == 0) { red3[w] = a; red3[4 + w] = b; red3[8 + w] = c; }
  __syncthreads();
  a = red3[0] + red3[1] + red3[2] + red3[3];
  b = red3[4] + red3[5] + red3[6] + red3[7];
  c = red3[8] + red3[9] + red3[10] + red3[11];
}

// ---------------- fused x->bf16 convert + sigmoid row gate ----------------

__global__ __launch_bounds__(256) void cvtsig_kernel(
    const float4* __restrict__ x, const float* __restrict__ att_w,
    const float* __restrict__ att_b, ushort4* __restrict__ xb, float* __restrict__ sig)
{
  int row  = blockIdx.x * 4 + (threadIdx.x >> 6);
  int lane = threadIdx.x & 63;
  const float4* xr = x + (size_t)row * (DIN / 4);
  const float4* wr = (const float4*)att_w;
  ushort4* xo = xb + (size_t)row * (DIN / 4);
  float acc = 0.f;
#pragma unroll
  for (int k = 0; k < DIN / 4 / 64; ++k) {   // 5
    float4 a = xr[lane + k * 64];
    float4 w = wr[lane + k * 64];
    acc += a.x * w.x + a.y * w.y + a.z * w.z + a.w * w.w;
    ushort4 o;
    o.x = f2bf(a.x); o.y = f2bf(a.y); o.z = f2bf(a.z); o.w = f2bf(a.w);
    xo[lane + k * 64] = o;
  }
  acc = warpReduceSum(acc);
  if (lane == 0) sig[row] = 1.f / (1.f + expf(-(acc + att_b[0])));
}

// ---------------- weight converts ----------------

// out[n][koff+k] = bf16(W[k][n]); out row-stride ostride.
__global__ __launch_bounds__(256) void wcvt_kernel(const float* __restrict__ W,
                                                   ushort* __restrict__ out,
                                                   int K, int N, int ostride, int koff) {
  __shared__ float t[32][33];
  int n0 = blockIdx.x * 32, k0 = blockIdx.y * 32;
  int tx = threadIdx.x & 31, ty = threadIdx.x >> 5;
#pragma unroll
  for (int r = 0; r < 4; ++r) {
    int k = ty + r * 8;
    t[k][tx] = W[(size_t)(k0 + k) * N + n0 + tx];
  }
  __syncthreads();
#pragma unroll
  for (int r = 0; r < 4; ++r) {
    int nn = ty + r * 8;
    out[(size_t)(n0 + nn) * ostride + koff + k0 + tx] = f2bf(t[tx][nn]);
  }
}

// wpw[n][k] = n<41 ? bf16(w2[k][n]) : 0   (128 x 512)
__global__ __launch_bounds__(256) void w2cvt_kernel(const float* __restrict__ w2,
                                                    ushort* __restrict__ wpw) {
  int idx = blockIdx.x * 256 + threadIdx.x;
  int n = idx >> 9, k = idx & 511;
  wpw[idx] = (n < S) ? f2bf(w2[(size_t)k * S + n]) : (ushort)0;
}

// ---------------- bf16 MFMA GEMM: C = A[M,K] @ Bt[N,K]^T, column-block epilogues ----------------

struct Epi {
  void* dst0; void* dst1; void* dst2;
  const float* bias0; const float* bias1; const float* bias2;
  const float* rs0;            // rowscale, branch 0 only
  int n1, n2;                  // col boundaries
  int ld0, ld1, ld2;
  int relu2;                   // relu, branch 2 only
};

template<bool F32OUT>
__global__ __launch_bounds__(256) void gemm_bf16(
    const ushort* __restrict__ A, const ushort* __restrict__ Bt, int K, Epi e)
{
  __shared__ __align__(16) ushort As[128 * 32];
  __shared__ __align__(16) ushort Bs[128 * 32];

  const int tid  = threadIdx.x;
  const int w    = tid >> 6;
  const int lane = tid & 63;
  const int l16  = lane & 15;
  const int l4   = lane >> 4;
  const int bm   = blockIdx.y * 128;
  const int bn   = blockIdx.x * 128;
  const int m0   = (w >> 1) * 64;
  const int n0   = (w & 1) * 64;

  const int srow = w * 32 + (lane >> 2);
  const int scol = (lane & 3) * 8;

  f32x4 acc[4][4];
#pragma unroll
  for (int i = 0; i < 4; ++i)
#pragma unroll
    for (int j = 0; j < 4; ++j) acc[i][j] = (f32x4)0.f;

  const ushort* pA0 = A  + (size_t)(bm + srow) * K + scol;
  const ushort* pA1 = A  + (size_t)(bm + srow + 16) * K + scol;
  const ushort* pB0 = Bt + (size_t)(bn + srow) * K + scol;
  const ushort* pB1 = Bt + (size_t)(bn + srow + 16) * K + scol;
  ushort* lA0 = &As[w * 1024];
  ushort* lA1 = &As[w * 1024 + 512];
  ushort* lB0 = &Bs[w * 1024];
  ushort* lB1 = &Bs[w * 1024 + 512];

  for (int kt = 0; kt < K; kt += 32) {
    gload16(pA0 + kt, lA0);
    gload16(pA1 + kt, lA1);
    gload16(pB0 + kt, lB0);
    gload16(pB1 + kt, lB1);
    __syncthreads();

    short8 a[4], b[4];
#pragma unroll
    for (int i = 0; i < 4; ++i)
      a[i] = *reinterpret_cast<const short8*>(&As[(m0 + i * 16 + l16) * 32 + l4 * 8]);
#pragma unroll
    for (int j = 0; j < 4; ++j)
      b[j] = *reinterpret_cast<const short8*>(&Bs[(n0 + j * 16 + l16) * 32 + l4 * 8]);
#pragma unroll
    for (int i = 0; i < 4; ++i)
#pragma unroll
      for (int j = 0; j < 4; ++j)
        acc[i][j] = __builtin_amdgcn_mfma_f32_16x16x32_bf16(a[i], b[j], acc[i][j], 0, 0, 0);
    __syncthreads();
  }

  void* dstv; const float* bias; const float* rs = nullptr; int ldc, cb, relu = 0;
  if (bn < e.n1)      { dstv = e.dst0; ldc = e.ld0; cb = bn;        bias = e.bias0; rs = e.rs0; }
  else if (bn < e.n2) { dstv = e.dst1; ldc = e.ld1; cb = bn - e.n1; bias = e.bias1; }
  else                { dstv = e.dst2; ldc = e.ld2; cb = bn - e.n2; bias = e.bias2; relu = e.relu2; }

#pragma unroll
  for (int i = 0; i < 4; ++i) {
    int mbase = bm + m0 + i * 16 + l4 * 4;
    float rsv[4];
#pragma unroll
    for (int r = 0; r < 4; ++r) rsv[r] = rs ? rs[mbase + r] : 1.f;
#pragma unroll
    for (int j = 0; j < 4; ++j) {
      int col = cb + n0 + j * 16 + l16;
      float bv = bias ? bias[col] : 0.f;
#pragma unroll
      for (int r = 0; r < 4; ++r) {
        float t = acc[i][j][r] * rsv[r] + bv;
        if (relu) t = fmaxf(t, 0.f);
        if (F32OUT) ((float*)dstv)[(size_t)(mbase + r) * ldc + col] = t;
        else        ((ushort*)dstv)[(size_t)(mbase + r) * ldc + col] = f2bf(t);
      }
    }
  }
}

// ---------------- GCN tridiagonal aggregate + bias + LN -> out ----------------

__device__ __forceinline__ float dinv_local(int j) {
  return rsqrtf((j == 0 || j == S - 1) ? 3.f : 5.f);
}

__global__ __launch_bounds__(256) void gcnln_kernel(
    const ushort* __restrict__ h, const float* __restrict__ gcn_b,
    const float* __restrict__ g, const float* __restrict__ be, float* __restrict__ out)
{
  int n = blockIdx.x;
  int i = n % S;
  int tid = threadIdx.x;
  int d0 = tid * 4;
  float di = dinv_local(i);
  float wc = di * di;
  float wl = (i > 0)     ? 2.f * di * dinv_local(i - 1) : 0.f;
  float wr = (i < S - 1) ? 2.f * di * dinv_local(i + 1) : 0.f;
  const ushort* hc = h + (size_t)n * DOUT + d0;
  ushort4 c4 = *(const ushort4*)hc;
  ushort4 lft = (i > 0)     ? *(const ushort4*)(hc - DOUT) : ushort4{0, 0, 0, 0};
  ushort4 rgt = (i < S - 1) ? *(const ushort4*)(hc + DOUT) : ushort4{0, 0, 0, 0};
  float4 b4 = *(const float4*)(gcn_b + d0);
  float vals[4];
  const ushort* cp = (const ushort*)&c4;
  const ushort* lp = (const ushort*)&lft;
  const ushort* rp = (const ushort*)&rgt;
  const float* bp = (const float*)&b4;
  float s = 0.f, sq = 0.f;
#pragma unroll
  for (int q = 0; q < 4; ++q) {
    float v = wc * bf2f(cp[q]) + wl * bf2f(lp[q]) + wr * bf2f(rp[q]) + bp[q];
    vals[q] = v;
    s += v; sq += v * v;
  }
  blockReduce2(s, sq);
  float mu = s * (1.f / DOUT);
  float var = sq * (1.f / DOUT) - mu * mu;
  float rstd = rsqrtf(var + 1e-5f);
  float4 g4 = *(const float4*)(g + d0);
  float4 e4 = *(const float4*)(be + d0);
  const float* gp = (const float*)&g4;
  const float* ep = (const float*)&e4;
  float4 o4;
  float* op = (float*)&o4;
#pragma unroll
  for (int q = 0; q < 4; ++q) op[q] = (vals[q] - mu) * rstd * gp[q] + ep[q];
  *(float4*)(out + (size_t)n * DOUT + d0) = o4;
}

// ---------------- fused GAT: per (batch, region-block) ----------------

__global__ __launch_bounds__(256) void gat_fused(
    const ushort* __restrict__ h, const float* __restrict__ as_,
    const float* __restrict__ ad_, const float* __restrict__ gat_b,
    const float* __restrict__ g, const float* __restrict__ be,
    float* __restrict__ out)
{
  int b  = blockIdx.x >> 2;
  int rb = blockIdx.x & 3;
  int lo = rb * 13;
  int cnt = (rb < 3) ? 13 : 2;
  __shared__ __align__(16) ushort hs[13][DOUT];
  __shared__ float alpha[13][13][HEADS];
  __shared__ float als_l[13][HEADS], ald_l[13][HEADS];
  int tid = threadIdx.x;
  int wv = tid >> 6, lane = tid & 63;

  // a) stage rows in LDS
  for (int r = 0; r < cnt; ++r) {
    const ushort4* src = (const ushort4*)(h + (size_t)(b * S + lo + r) * DOUT);
    ((ushort4*)hs[r])[tid] = src[tid];
  }
  __syncthreads();

  // b) attention logits: wave = head
  {
    const float4* a4 = (const float4*)(as_ + wv * HC);
    const float4* d4 = (const float4*)(ad_ + wv * HC);
    float4 av = a4[lane], dv = d4[lane];
    for (int s = 0; s < cnt; ++s) {
      ushort4 hv4 = ((const ushort4*)&hs[s][wv * HC])[lane];
      float h0 = bf2f(hv4.x), h1 = bf2f(hv4.y), h2 = bf2f(hv4.z), h3 = bf2f(hv4.w);
      float a = h0 * av.x + h1 * av.y + h2 * av.z + h3 * av.w;
      float d = h0 * dv.x + h1 * dv.y + h2 * dv.z + h3 * dv.w;
      a = warpReduceSum(a);
      d = warpReduceSum(d);
      if (lane == 0) { als_l[s][wv] = a; ald_l[s][wv] = d; }
    }
  }
  __syncthreads();

  // c) softmax alpha: thread = (target, head)
  if (tid < cnt * HEADS) {
    int t = tid >> 2, hd = tid & 3;
    float myald = ald_l[t][hd];
    float m = -1e30f;
    for (int s = 0; s < cnt; ++s) {
      float v = als_l[s][hd] + myald;
      v = (v > 0.f) ? v : 0.2f * v;
      m = fmaxf(m, v);
    }
    float den = 0.f;
    for (int s = 0; s < cnt; ++s) {
      float v = als_l[s][hd] + myald;
      v = (v > 0.f) ? v : 0.2f * v;
      float ev = expf(v - m) * ((s == t) ? 1.f : 2.f);  // duplicate edges -> weight 2
      alpha[t][s][hd] = ev;
      den += ev;
    }
    float inv = 1.f / den;
    for (int s = 0; s < cnt; ++s) alpha[t][s][hd] *= inv;
  }
  __syncthreads();

  // d) aggregate + LN per target row
  float gbv[4], gv[4], ev[4];
#pragma unroll
  for (int q = 0; q < 4; ++q) {
    int d = q * 256 + tid;
    gbv[q] = gat_b[d]; gv[q] = g[d]; ev[q] = be[d];
  }
  for (int t = 0; t < cnt; ++t) {
    float vals[4];
    float s = 0.f, sq = 0.f;
#pragma unroll
    for (int q = 0; q < 4; ++q) {
      int d = q * 256 + tid;
      float accv = 0.f;
      for (int si = 0; si < cnt; ++si)
        accv += alpha[t][si][q] * bf2f(hs[si][d]);
      accv += gbv[q];
      vals[q] = accv;
      s += accv; sq += accv * accv;
    }
    blockReduce2(s, sq);
    float mu = s * (1.f / DOUT);
    float var = sq * (1.f / DOUT) - mu * mu;
    float rstd = rsqrtf(var + 1e-5f);
    float* o = out + (size_t)(b * S + lo + t) * DOUT;
#pragma unroll
    for (int q = 0; q < 4; ++q) {
      int d = q * 256 + tid;
      o[d] = (vals[q] - mu) * rstd * gv[q] + ev[q];
    }
    __syncthreads();   // protect blockReduce2's shared buffer across iterations
  }
}

// ---------------- sage_in: softmax(fp2+b2) @ x, prefix-mean agg -> interleaved bf16 ----------------

__global__ __launch_bounds__(256) void sagein_kernel(
    const float* __restrict__ fp2, const float* __restrict__ fp_b2,
    const ushort* __restrict__ xb, ushort* __restrict__ sa)
{
  int b = blockIdx.y;
  int d0 = blockIdx.x * 256;
  int tid = threadIdx.x, wv = tid >> 6, lane = tid & 63;
  __shared__ float pws[S][S];
  for (int i = wv; i < S; i += 4) {
    float v = (lane < S) ? (fp2[(size_t)(b * S + i) * 128 + lane] + fp_b2[lane]) : -1e30f;
    float m = v;
#pragma unroll
    for (int off = 32; off; off >>= 1) m = fmaxf(m, __shfl_xor(m, off));
    float e = (lane < S) ? expf(v - m) : 0.f;
    float sum = e;
#pragma unroll
    for (int off = 32; off; off >>= 1) sum += __shfl_xor(sum, off);
    if (lane < S) pws[i][lane] = e / sum;
  }
  __syncthreads();
  float xreg[S];
  const ushort* xp = xb + (size_t)b * S * DIN + d0 + tid;
#pragma unroll
  for (int j = 0; j < S; ++j) xreg[j] = bf2f(xp[(size_t)j * DIN]);
  float prefix = 0.f;
  for (int i = 0; i < S; ++i) {
    float v = 0.f;
#pragma unroll
    for (int j = 0; j < S; ++j) v += pws[i][j] * xreg[j];
    size_t base = (size_t)(b * S + i) * (2 * DIN) + d0 + tid;
    sa[base] = f2bf(v);
    sa[base + DIN] = f2bf((i > 0) ? (prefix / (float)i) : 0.f);
    prefix += v;
  }
}

// ---------------- fused sage-LN + gated mixing ----------------

__global__ __launch_bounds__(256) void lngate_kernel(
    const ushort* __restrict__ hbuf, const float* __restrict__ dn_g,
    const float* __restrict__ dn_b, const float* __restrict__ gw,
    const float* __restrict__ gb, float* __restrict__ out, int N)
{
  size_t OUT = (size_t)N * DOUT;
  int n = blockIdx.x;
  int tid = threadIdx.x;
  int d0 = tid * 4;

  // LN of sage row
  ushort4 h4 = *(const ushort4*)(hbuf + (size_t)n * DOUT + d0);
  const ushort* hp = (const ushort*)&h4;
  float hv[4];
  float s = 0.f, sq = 0.f;
#pragma unroll
  for (int q = 0; q < 4; ++q) {
    hv[q] = bf2f(hp[q]);
    s += hv[q]; sq += hv[q] * hv[q];
  }
  blockReduce2(s, sq);
  float mu = s * (1.f / DOUT);
  float var = sq * (1.f / DOUT) - mu * mu;
  float rstd = rsqrtf(var + 1e-5f);
  float4 g4 = *(const float4*)(dn_g + d0);
  float4 b4 = *(const float4*)(dn_b + d0);
  const float* gp = (const float*)&g4;
  const float* bp = (const float*)&b4;
  float sa_[4];
#pragma unroll
  for (int q = 0; q < 4; ++q) sa_[q] = (hv[q] - mu) * rstd * gp[q] + bp[q];

  // read shallow / gat rows
  float4 sh4 = *(const float4*)(out + (size_t)n * DOUT + d0);
  float4 ga4 = *(const float4*)(out + OUT + (size_t)n * DOUT + d0);
  const float* shp = (const float*)&sh4;
  const float* gap = (const float*)&ga4;

  // gate logits
  float p0 = 0.f, p1 = 0.f, p2 = 0.f;
#pragma unroll
  for (int q = 0; q < 4; ++q) {
    int d = d0 + q;
    const float* w0 = gw + (size_t)d * 3;
    const float* w1 = gw + (size_t)(DOUT + d) * 3;
    const float* w2 = gw + (size_t)(2 * DOUT + d) * 3;
    p0 += shp[q] * w0[0] + gap[q] * w1[0] + sa_[q] * w2[0];
    p1 += shp[q] * w0[1] + gap[q] * w1[1] + sa_[q] * w2[1];
    p2 += shp[q] * w0[2] + gap[q] * w1[2] + sa_[q] * w2[2];
  }
  blockReduce3(p0, p1, p2);
  p0 += gb[0]; p1 += gb[1]; p2 += gb[2];
  float m = fmaxf(p0, fmaxf(p1, p2));
  float e0 = expf(p0 - m), e1 = expf(p1 - m), e2 = expf(p2 - m);
  float inv = 1.f / (e0 + e1 + e2);
  float g0 = e0 * inv, g1 = e1 * inv, g2 = e2 * inv;
  float4 o4;
  float* op = (float*)&o4;
#pragma unroll
  for (int q = 0; q < 4; ++q) op[q] = g0 * shp[q] + g1 * gap[q] + g2 * sa_[q];
  *(float4*)(out + 2 * OUT + (size_t)n * DOUT + d0) = o4;
}

// ---------------- launch ----------------

extern "C" void kernel_launch(void* const* d_in, const int* in_sizes, int n_in,
                              void* d_out, int out_size, void* d_ws, size_t ws_size,
                              hipStream_t stream) {
  const float* x       = (const float*)d_in[0];
  const float* att_w   = (const float*)d_in[1];
  const float* att_b   = (const float*)d_in[2];
  const float* gcn_w   = (const float*)d_in[3];
  const float* gcn_b   = (const float*)d_in[4];
  const float* sn_g    = (const float*)d_in[5];
  const float* sn_b    = (const float*)d_in[6];
  const float* gat_w   = (const float*)d_in[7];
  const float* gat_as  = (const float*)d_in[8];
  const float* gat_ad  = (const float*)d_in[9];
  const float* gat_b   = (const float*)d_in[10];
  const float* mn_g    = (const float*)d_in[11];
  const float* mn_b    = (const float*)d_in[12];
  const float* sage_wl = (const float*)d_in[13];
  const float* sage_bl = (const float*)d_in[14];
  const float* sage_wr = (const float*)d_in[15];
  const float* fp_w1   = (const float*)d_in[16];
  const float* fp_b1   = (const float*)d_in[17];
  const float* fp_w2   = (const float*)d_in[18];
  const float* fp_b2   = (const float*)d_in[19];
  const float* dn_g    = (const float*)d_in[20];
  const float* dn_b    = (const float*)d_in[21];
  const float* gate_w  = (const float*)d_in[22];
  const float* gate_b  = (const float*)d_in[23];

  const int B = in_sizes[0] / (S * DIN);   // 512
  const int N = B * S;                     // 20992 = 164*128
  float* out = (float*)d_out;

  char* ws = (char*)d_ws;
  size_t off = 0;
  auto alloc = [&](size_t bytes) { size_t p = off; off += (bytes + 255) & ~(size_t)255; return p; };
  ushort* xb   = (ushort*)(ws + alloc((size_t)N * DIN * 2));          // 53.7 MB
  ushort* Bt1  = (ushort*)(ws + alloc((size_t)2560 * DIN * 2));       // 6.6 MB
  ushort* Bt2  = (ushort*)(ws + alloc((size_t)DOUT * 2 * DIN * 2));   // 5.2 MB
  ushort* wpw  = (ushort*)(ws + alloc((size_t)128 * 512 * 2));        // 0.13 MB
  ushort* gcnh = (ushort*)(ws + alloc((size_t)N * DOUT * 2));         // 43 MB (later: hbuf)
  ushort* Cgat = (ushort*)(ws + alloc((size_t)N * DOUT * 2));         // 43 MB (later: fp2)
  ushort* fp1  = (ushort*)(ws + alloc((size_t)N * 512 * 2));          // 21.5 MB
  ushort* sa   = (ushort*)(ws + alloc((size_t)N * 2 * DIN * 2));      // 107.5 MB
  float*  sig  = (float*)(ws + alloc((size_t)N * 4));
  float*  fp2  = (float*)Cgat;   // N x 128 f32 (10.7 MB) — Cgat dead after gat_fused
  ushort* hbuf = gcnh;           // sage GEMM out — gcnh dead after gcnln

  dim3 blk(256);

  // converts + sigmoid gate
  cvtsig_kernel<<<N / 4, blk, 0, stream>>>((const float4*)x, att_w, att_b, (ushort4*)xb, sig);
  wcvt_kernel<<<dim3(DOUT / 32, DIN / 32), blk, 0, stream>>>(gcn_w, Bt1, DIN, DOUT, DIN, 0);
  wcvt_kernel<<<dim3(DOUT / 32, DIN / 32), blk, 0, stream>>>(gat_w, Bt1 + (size_t)1024 * DIN, DIN, DOUT, DIN, 0);
  wcvt_kernel<<<dim3(512 / 32, DIN / 32), blk, 0, stream>>>(fp_w1, Bt1 + (size_t)2048 * DIN, DIN, 512, DIN, 0);
  wcvt_kernel<<<dim3(DOUT / 32, DIN / 32), blk, 0, stream>>>(sage_wr, Bt2, DIN, DOUT, 2 * DIN, 0);
  wcvt_kernel<<<dim3(DOUT / 32, DIN / 32), blk, 0, stream>>>(sage_wl, Bt2, DIN, DOUT, 2 * DIN, DIN);
  w2cvt_kernel<<<dim3(128 * 512 / 256), blk, 0, stream>>>(fp_w2, wpw);

  // GEMM1: xb @ [gcn_w | gat_w | fp_w1]  (N=2560) -> bf16 outs
  Epi e1;
  e1.dst0 = gcnh; e1.dst1 = Cgat; e1.dst2 = fp1;
  e1.bias0 = nullptr; e1.bias1 = nullptr; e1.bias2 = fp_b1;
  e1.rs0 = sig;
  e1.n1 = 1024; e1.n2 = 2048;
  e1.ld0 = DOUT; e1.ld1 = DOUT; e1.ld2 = 512;
  e1.relu2 = 1;
  gemm_bf16<false><<<dim3(2560 / 128, N / 128), blk, 0, stream>>>(xb, Bt1, DIN, e1);

  // shallow: stencil + LN
  gcnln_kernel<<<N, blk, 0, stream>>>(gcnh, gcn_b, sn_g, sn_b, out);

  // medium: fully fused GAT per region block
  gat_fused<<<B * 4, blk, 0, stream>>>(Cgat, gat_as, gat_ad, gat_b, mn_g, mn_b,
                                       out + (size_t)N * DOUT);

  // deep: fp2 GEMM (N=128 padded) -> softmax+mix+prefix -> SAGE GEMM -> LN+gate
  Epi epw;
  epw.dst0 = fp2; epw.dst1 = nullptr; epw.dst2 = nullptr;
  epw.bias0 = nullptr; epw.bias1 = nullptr; epw.bias2 = nullptr;
  epw.rs0 = nullptr;
  epw.n1 = 1 << 30; epw.n2 = 1 << 30;
  epw.ld0 = 128; epw.ld1 = 128; epw.ld2 = 128;
  epw.relu2 = 0;
  gemm_bf16<true><<<dim3(1, N / 128), blk, 0, stream>>>(fp1, wpw, 512, epw);

  sagein_kernel<<<dim3(DIN / 256, B), blk, 0, stream>>>(fp2, fp_b2, xb, sa);

  Epi e2;
  e2.dst0 = hbuf; e2.dst1 = nullptr; e2.dst2 = nullptr;
  e2.bias0 = sage_bl; e2.bias1 = nullptr; e2.bias2 = nullptr;
  e2.rs0 = nullptr;
  e2.n1 = 1 << 30; e2.n2 = 1 << 30;
  e2.ld0 = DOUT; e2.ld1 = DOUT; e2.ld2 = DOUT;
  e2.relu2 = 0;
  gemm_bf16<false><<<dim3(DOUT / 128, N / 128), blk, 0, stream>>>(sa, Bt2, 2 * DIN, e2);

  lngate_kernel<<<N, blk, 0, stream>>>(hbuf, dn_g, dn_b, gate_w, gate_b, out, N);
}